// Round 1
// baseline (62.657 us; speedup 1.0000x reference)
//
#include <hip/hip_runtime.h>
#include <math.h>

// Problem constants: B=16, N=128, h=256, goal_dim=64, obs_dim=128, local=64, skills=16

// ---- workspace layout (float offsets) ----
#define WQT_OFF 0         // [64][256]
#define WKT_OFF 16384     // [128][256]
#define WVT_OFF 49152     // [128][256]
#define WOT_OFF 81920     // [256][256]
#define Q_OFF   147456    // [2048][256]
#define KT_OFF  671744    // [16][256][128]  (K transposed per batch)
#define V_OFF   1196032   // [2048][256]
// total 1720320 floats = 6.9 MB

// ---- output layout (float offsets, tuple return order) ----
#define LOGIT_OFF 0        // [16][128][16]
#define MASK_OFF  32768    // [16][128][128]
#define ATTN_OFF  294912   // [16][128][128]
#define OUT_OFF   557056   // [16][128][256]

__global__ __launch_bounds__(256) void transpose_k(
    const float* __restrict__ Wq, const float* __restrict__ Wk,
    const float* __restrict__ Wv, const float* __restrict__ Wo,
    float* __restrict__ ws) {
  int idx = blockIdx.x * 256 + threadIdx.x;
  if (idx < 16384) {                      // WqT[i][o], I=64, O=256
    int i = idx >> 8, o = idx & 255;
    ws[WQT_OFF + idx] = Wq[o * 64 + i];
  } else if (idx < 49152) {               // WkT, I=128, O=256
    int j = idx - 16384; int i = j >> 8, o = j & 255;
    ws[WKT_OFF + j] = Wk[o * 128 + i];
  } else if (idx < 81920) {               // WvT
    int j = idx - 49152; int i = j >> 8, o = j & 255;
    ws[WVT_OFF + j] = Wv[o * 128 + i];
  } else if (idx < 147456) {              // WoT, I=256, O=256
    int j = idx - 81920; int i = j >> 8, o = j & 255;
    ws[WOT_OFF + j] = Wo[o * 256 + i];
  }
}

// blocks 0..127: Q (16 rows each).  blocks 128..383: K+V (8 rows each).
__global__ __launch_bounds__(256) void proj_k(
    const float* __restrict__ goals, const float* __restrict__ agents,
    const float* __restrict__ bq, const float* __restrict__ bk,
    const float* __restrict__ bv, float* __restrict__ ws) {
  const float* WqT = ws + WQT_OFF;
  const float* WkT = ws + WKT_OFF;
  const float* WvT = ws + WVT_OFF;
  float* Qo  = ws + Q_OFF;
  float* KTo = ws + KT_OFF;
  float* Vo  = ws + V_OFF;
  int t = threadIdx.x;
  int bid = blockIdx.x;
  if (bid < 128) {
    __shared__ __align__(16) float xs[16][64];
    int row0 = bid * 16;
    for (int i = t; i < 1024; i += 256) xs[i >> 6][i & 63] = goals[row0 * 64 + i];
    __syncthreads();
    float acc[16];
#pragma unroll
    for (int r = 0; r < 16; r++) acc[r] = 0.f;
    for (int d = 0; d < 64; d += 4) {
      float w0 = WqT[(d + 0) * 256 + t];
      float w1 = WqT[(d + 1) * 256 + t];
      float w2 = WqT[(d + 2) * 256 + t];
      float w3 = WqT[(d + 3) * 256 + t];
#pragma unroll
      for (int r = 0; r < 16; r++) {
        float4 x4 = *(const float4*)&xs[r][d];
        acc[r] = fmaf(w0, x4.x, acc[r]);
        acc[r] = fmaf(w1, x4.y, acc[r]);
        acc[r] = fmaf(w2, x4.z, acc[r]);
        acc[r] = fmaf(w3, x4.w, acc[r]);
      }
    }
    float bb = bq[t];
#pragma unroll
    for (int r = 0; r < 16; r++) Qo[(row0 + r) * 256 + t] = acc[r] + bb;
  } else {
    __shared__ __align__(16) float xs2[8][128];
    int row0 = (bid - 128) * 8;
    for (int i = t; i < 1024; i += 256) xs2[i >> 7][i & 127] = agents[row0 * 128 + i];
    __syncthreads();
    float accK[8], accV[8];
#pragma unroll
    for (int r = 0; r < 8; r++) { accK[r] = 0.f; accV[r] = 0.f; }
    for (int d = 0; d < 128; d += 4) {
      float k0 = WkT[(d + 0) * 256 + t], k1 = WkT[(d + 1) * 256 + t];
      float k2 = WkT[(d + 2) * 256 + t], k3 = WkT[(d + 3) * 256 + t];
      float v0 = WvT[(d + 0) * 256 + t], v1 = WvT[(d + 1) * 256 + t];
      float v2 = WvT[(d + 2) * 256 + t], v3 = WvT[(d + 3) * 256 + t];
#pragma unroll
      for (int r = 0; r < 8; r++) {
        float4 x4 = *(const float4*)&xs2[r][d];
        accK[r] = fmaf(k0, x4.x, accK[r]); accK[r] = fmaf(k1, x4.y, accK[r]);
        accK[r] = fmaf(k2, x4.z, accK[r]); accK[r] = fmaf(k3, x4.w, accK[r]);
        accV[r] = fmaf(v0, x4.x, accV[r]); accV[r] = fmaf(v1, x4.y, accV[r]);
        accV[r] = fmaf(v2, x4.z, accV[r]); accV[r] = fmaf(v3, x4.w, accV[r]);
      }
    }
    float bbk = bk[t], bbv = bv[t];
    int b = row0 >> 7, m0 = row0 & 127;
#pragma unroll
    for (int r = 0; r < 8; r++) {
      Vo[(row0 + r) * 256 + t] = accV[r] + bbv;
      KTo[(b * 256 + t) * 128 + m0 + r] = accK[r] + bbk;  // K transposed
    }
  }
}

// one block per (batch b, 8-row n tile): 256 blocks x 256 threads
__global__ __launch_bounds__(256) void attn_k(
    const float* __restrict__ goals, const float* __restrict__ agents_local,
    const float* __restrict__ u1, const float* __restrict__ u2,
    const float* __restrict__ bo, const float* __restrict__ Wsm,
    const float* __restrict__ bs, const float* __restrict__ ws,
    float* __restrict__ out) {
  const float* Q   = ws + Q_OFF;
  const float* KT  = ws + KT_OFF;
  const float* V   = ws + V_OFF;
  const float* WoT = ws + WOT_OFF;
  float* o_logit = out + LOGIT_OFF;
  float* o_mask  = out + MASK_OFF;
  float* o_attn  = out + ATTN_OFF;
  float* o_out   = out + OUT_OFF;

  int bid = blockIdx.x;
  int b  = bid >> 4;
  int n0 = (bid & 15) << 3;
  int t = threadIdx.x;

  __shared__ __align__(16) float q[8][256];
  __shared__ float part[2][128][9];          // stride 9: no bank conflicts
  __shared__ __align__(16) float wbuf[8][128];
  __shared__ __align__(16) float infob[8][256];
  __shared__ __align__(16) float outb[8][256];
  __shared__ float wred[2][8];
  __shared__ float wsum[2][8];

  // ---- load Q rows ----
  const float* qsrc = Q + (b * 128 + n0) * 256;
  for (int i = t; i < 2048; i += 256) q[i >> 8][i & 255] = qsrc[i];
  __syncthreads();

  // ---- phase 2: logits partials (thread = (m, half-of-h)) ----
  int m = t & 127, half = t >> 7;
  {
    const float* kp = KT + (b * 256 + half * 128) * 128 + m;
    float acc[8];
#pragma unroll
    for (int r = 0; r < 8; r++) acc[r] = 0.f;
    for (int i = 0; i < 128; i += 4) {
      float k0 = kp[(i + 0) * 128], k1 = kp[(i + 1) * 128];
      float k2 = kp[(i + 2) * 128], k3 = kp[(i + 3) * 128];
      int d = half * 128 + i;
#pragma unroll
      for (int r = 0; r < 8; r++) {
        float4 q4 = *(const float4*)&q[r][d];
        acc[r] = fmaf(k0, q4.x, acc[r]);
        acc[r] = fmaf(k1, q4.y, acc[r]);
        acc[r] = fmaf(k2, q4.z, acc[r]);
        acc[r] = fmaf(k3, q4.w, acc[r]);
      }
    }
#pragma unroll
    for (int r = 0; r < 8; r++) part[half][m][r] = acc[r];
  }
  __syncthreads();

  // ---- phase 3: gumbel-sigmoid mask, scores, softmax (threads 0..127 = m) ----
  float score[8], maskv[8], ev[8];
  if (t < 128) {
#pragma unroll
    for (int r = 0; r < 8; r++) {
      float l = (part[0][t][r] + part[1][t][r]) * 0.0625f;  // /sqrt(256)
      int row = b * 128 + n0 + r;
      float uu1 = u1[row * 128 + t];
      float uu2 = u2[row * 128 + t];
      float g1 = -logf(-logf(uu1 + 1e-20f) + 1e-20f);
      float g2 = -logf(-logf(uu2 + 1e-20f) + 1e-20f);
      float z = l + g1 - g2;                                 // TAU = 1
      float mk = 1.0f / (1.0f + expf(-z));
      maskv[r] = mk;
      o_mask[row * 128 + t] = mk;
      score[r] = l + logf(mk + 1e-8f);
    }
    float mx[8];
#pragma unroll
    for (int r = 0; r < 8; r++) {
      float v = score[r];
      for (int off = 32; off >= 1; off >>= 1) v = fmaxf(v, __shfl_xor(v, off));
      mx[r] = v;
    }
    if ((t & 63) == 0) {
#pragma unroll
      for (int r = 0; r < 8; r++) wred[t >> 6][r] = mx[r];
    }
  }
  __syncthreads();
  if (t < 128) {
    float sm[8];
#pragma unroll
    for (int r = 0; r < 8; r++) {
      float rmax = fmaxf(wred[0][r], wred[1][r]);
      float e = expf(score[r] - rmax);
      ev[r] = e;
      float s = e;
      for (int off = 32; off >= 1; off >>= 1) s += __shfl_xor(s, off);
      sm[r] = s;
    }
    if ((t & 63) == 0) {
#pragma unroll
      for (int r = 0; r < 8; r++) wsum[t >> 6][r] = sm[r];
    }
  }
  __syncthreads();
  if (t < 128) {
#pragma unroll
    for (int r = 0; r < 8; r++) {
      float rsum = wsum[0][r] + wsum[1][r];
      float attn = ev[r] / rsum;
      int row = b * 128 + n0 + r;
      o_attn[row * 128 + t] = attn;
      wbuf[r][t] = attn * maskv[r];
    }
  }
  __syncthreads();

  // ---- phase 4: info[h] = sum_m w[m] * V[b,m,h]  (thread = h) ----
  float acc2[8];
#pragma unroll
  for (int r = 0; r < 8; r++) acc2[r] = 0.f;
  {
    const float* vp = V + (b * 128) * 256 + t;
    for (int m2 = 0; m2 < 128; m2 += 4) {
      float v0 = vp[(m2 + 0) * 256], v1 = vp[(m2 + 1) * 256];
      float v2 = vp[(m2 + 2) * 256], v3 = vp[(m2 + 3) * 256];
#pragma unroll
      for (int r = 0; r < 8; r++) {
        float4 w4 = *(const float4*)&wbuf[r][m2];
        acc2[r] = fmaf(v0, w4.x, acc2[r]);
        acc2[r] = fmaf(v1, w4.y, acc2[r]);
        acc2[r] = fmaf(v2, w4.z, acc2[r]);
        acc2[r] = fmaf(v3, w4.w, acc2[r]);
      }
    }
  }
#pragma unroll
  for (int r = 0; r < 8; r++) infob[r][t] = acc2[r];
  __syncthreads();

  // ---- phase 5: out[g] = sum_h WoT[h][g] * info[h] + bo  (thread = g) ----
  float acc3[8];
#pragma unroll
  for (int r = 0; r < 8; r++) acc3[r] = 0.f;
  {
    const float* wop = WoT + t;
    for (int h = 0; h < 256; h += 4) {
      float w0 = wop[(h + 0) * 256], w1 = wop[(h + 1) * 256];
      float w2 = wop[(h + 2) * 256], w3 = wop[(h + 3) * 256];
#pragma unroll
      for (int r = 0; r < 8; r++) {
        float4 i4 = *(const float4*)&infob[r][h];
        acc3[r] = fmaf(w0, i4.x, acc3[r]);
        acc3[r] = fmaf(w1, i4.y, acc3[r]);
        acc3[r] = fmaf(w2, i4.z, acc3[r]);
        acc3[r] = fmaf(w3, i4.w, acc3[r]);
      }
    }
  }
  float bov = bo[t];
#pragma unroll
  for (int r = 0; r < 8; r++) {
    float ov = acc3[r] + bov;
    int row = b * 128 + n0 + r;
    o_out[row * 256 + t] = ov;
    outb[r][t] = ov;
  }
  __syncthreads();

  // ---- phase 6: skill logits (threads 0..127: r = t>>4, s = t&15) ----
  if (t < 128) {
    int r = t >> 4, s = t & 15;
    int row = b * 128 + n0 + r;
    float acc = bs[s];
    const float* wsr = Wsm + s * 384;
    const float* lp = agents_local + row * 64;
    const float* gp = goals + row * 64;
    for (int c = 0; c < 64; c++)  acc = fmaf(wsr[c],       lp[c],      acc);
    for (int c = 0; c < 64; c++)  acc = fmaf(wsr[64 + c],  gp[c],      acc);
    for (int c = 0; c < 256; c++) acc = fmaf(wsr[128 + c], outb[r][c], acc);
    o_logit[row * 16 + s] = acc;
  }
}

extern "C" void kernel_launch(void* const* d_in, const int* in_sizes, int n_in,
                              void* d_out, int out_size, void* d_ws, size_t ws_size,
                              hipStream_t stream) {
  const float* goals        = (const float*)d_in[0];
  const float* agents       = (const float*)d_in[1];
  const float* agents_local = (const float*)d_in[2];
  const float* u1           = (const float*)d_in[3];
  const float* u2           = (const float*)d_in[4];
  const float* Wq = (const float*)d_in[5];
  const float* bq = (const float*)d_in[6];
  const float* Wk = (const float*)d_in[7];
  const float* bk = (const float*)d_in[8];
  const float* Wv = (const float*)d_in[9];
  const float* bv = (const float*)d_in[10];
  const float* Wo = (const float*)d_in[11];
  const float* bo = (const float*)d_in[12];
  const float* Wsm = (const float*)d_in[13];
  const float* bs  = (const float*)d_in[14];
  float* out = (float*)d_out;
  float* ws  = (float*)d_ws;

  transpose_k<<<576, 256, 0, stream>>>(Wq, Wk, Wv, Wo, ws);
  proj_k<<<384, 256, 0, stream>>>(goals, agents, bq, bk, bv, ws);
  attn_k<<<256, 256, 0, stream>>>(goals, agents_local, u1, u2, bo, Wsm, bs, ws, out);
}

// Round 2
// 42.681 us; speedup vs baseline: 1.4680x; 1.4680x over previous
//
#include <hip/hip_runtime.h>
#include <math.h>

// Problem constants: B=16, N=128, h=256, goal_dim=64, obs_dim=128, local=64, skills=16

// ---- workspace layout (float offsets) ----
#define WQT_OFF 0         // [64][256]
#define WKT_OFF 16384     // [128][256]
#define WVT_OFF 49152     // [128][256]
#define WOT_OFF 81920     // [256][256]
#define Q_OFF   147456    // [2048][256]
#define KT_OFF  671744    // [16][256][128]  (K transposed per batch)
#define V_OFF   1196032   // [2048][256]

// ---- output layout (float offsets, tuple return order) ----
#define LOGIT_OFF 0        // [16][128][16]
#define MASK_OFF  32768    // [16][128][128]
#define ATTN_OFF  294912   // [16][128][128]
#define OUT_OFF   557056   // [16][128][256]

__global__ __launch_bounds__(256) void transpose_k(
    const float* __restrict__ Wq, const float* __restrict__ Wk,
    const float* __restrict__ Wv, const float* __restrict__ Wo,
    float* __restrict__ ws) {
  int idx = blockIdx.x * 256 + threadIdx.x;
  if (idx < 16384) {                      // WqT[i][o], I=64, O=256
    int i = idx >> 8, o = idx & 255;
    ws[WQT_OFF + idx] = Wq[o * 64 + i];
  } else if (idx < 49152) {               // WkT, I=128, O=256
    int j = idx - 16384; int i = j >> 8, o = j & 255;
    ws[WKT_OFF + j] = Wk[o * 128 + i];
  } else if (idx < 81920) {               // WvT
    int j = idx - 49152; int i = j >> 8, o = j & 255;
    ws[WVT_OFF + j] = Wv[o * 128 + i];
  } else if (idx < 147456) {              // WoT, I=256, O=256
    int j = idx - 81920; int i = j >> 8, o = j & 255;
    ws[WOT_OFF + j] = Wo[o * 256 + i];
  }
}

// blocks 0..127: Q (16 rows each).  blocks 128..383: K+V (8 rows each).
__global__ __launch_bounds__(256) void proj_k(
    const float* __restrict__ goals, const float* __restrict__ agents,
    const float* __restrict__ bq, const float* __restrict__ bk,
    const float* __restrict__ bv, float* __restrict__ ws) {
  const float* WqT = ws + WQT_OFF;
  const float* WkT = ws + WKT_OFF;
  const float* WvT = ws + WVT_OFF;
  float* Qo  = ws + Q_OFF;
  float* KTo = ws + KT_OFF;
  float* Vo  = ws + V_OFF;
  int t = threadIdx.x;
  int bid = blockIdx.x;
  if (bid < 128) {
    __shared__ __align__(16) float xs[16][64];
    int row0 = bid * 16;
    for (int i = t; i < 1024; i += 256) xs[i >> 6][i & 63] = goals[row0 * 64 + i];
    __syncthreads();
    float acc[16];
#pragma unroll
    for (int r = 0; r < 16; r++) acc[r] = 0.f;
    for (int d = 0; d < 64; d += 4) {
      float w0 = WqT[(d + 0) * 256 + t];
      float w1 = WqT[(d + 1) * 256 + t];
      float w2 = WqT[(d + 2) * 256 + t];
      float w3 = WqT[(d + 3) * 256 + t];
#pragma unroll
      for (int r = 0; r < 16; r++) {
        float4 x4 = *(const float4*)&xs[r][d];
        acc[r] = fmaf(w0, x4.x, acc[r]);
        acc[r] = fmaf(w1, x4.y, acc[r]);
        acc[r] = fmaf(w2, x4.z, acc[r]);
        acc[r] = fmaf(w3, x4.w, acc[r]);
      }
    }
    float bb = bq[t];
#pragma unroll
    for (int r = 0; r < 16; r++) Qo[(row0 + r) * 256 + t] = acc[r] + bb;
  } else {
    __shared__ __align__(16) float xs2[8][128];
    int row0 = (bid - 128) * 8;
    for (int i = t; i < 1024; i += 256) xs2[i >> 7][i & 127] = agents[row0 * 128 + i];
    __syncthreads();
    float accK[8], accV[8];
#pragma unroll
    for (int r = 0; r < 8; r++) { accK[r] = 0.f; accV[r] = 0.f; }
    for (int d = 0; d < 128; d += 4) {
      float k0 = WkT[(d + 0) * 256 + t], k1 = WkT[(d + 1) * 256 + t];
      float k2 = WkT[(d + 2) * 256 + t], k3 = WkT[(d + 3) * 256 + t];
      float v0 = WvT[(d + 0) * 256 + t], v1 = WvT[(d + 1) * 256 + t];
      float v2 = WvT[(d + 2) * 256 + t], v3 = WvT[(d + 3) * 256 + t];
#pragma unroll
      for (int r = 0; r < 8; r++) {
        float4 x4 = *(const float4*)&xs2[r][d];
        accK[r] = fmaf(k0, x4.x, accK[r]); accK[r] = fmaf(k1, x4.y, accK[r]);
        accK[r] = fmaf(k2, x4.z, accK[r]); accK[r] = fmaf(k3, x4.w, accK[r]);
        accV[r] = fmaf(v0, x4.x, accV[r]); accV[r] = fmaf(v1, x4.y, accV[r]);
        accV[r] = fmaf(v2, x4.z, accV[r]); accV[r] = fmaf(v3, x4.w, accV[r]);
      }
    }
    float bbk = bk[t], bbv = bv[t];
    int b = row0 >> 7, m0 = row0 & 127;
#pragma unroll
    for (int r = 0; r < 8; r++) {
      Vo[(row0 + r) * 256 + t] = accV[r] + bbv;
      KTo[(b * 256 + t) * 128 + m0 + r] = accK[r] + bbk;  // K transposed
    }
  }
}

// one block per (batch b, 8-row n tile): 256 blocks x 1024 threads.
// b = bid & 15 so each batch's 16 tiles land on one XCD (bid % 8 fixed per b pair).
__global__ __launch_bounds__(1024, 4) void attn_k(
    const float* __restrict__ goals, const float* __restrict__ agents_local,
    const float* __restrict__ u1, const float* __restrict__ u2,
    const float* __restrict__ bo, const float* __restrict__ Wsm,
    const float* __restrict__ bs, const float* __restrict__ ws,
    float* __restrict__ out) {
  const float* Q   = ws + Q_OFF;
  const float* KT  = ws + KT_OFF;
  const float* V   = ws + V_OFF;
  const float* WoT = ws + WOT_OFF;
  float* o_logit = out + LOGIT_OFF;
  float* o_mask  = out + MASK_OFF;
  float* o_attn  = out + ATTN_OFF;
  float* o_out   = out + OUT_OFF;

  int bid = blockIdx.x;
  int b  = bid & 15;
  int n0 = (bid >> 4) << 3;
  int t = threadIdx.x;

  // LDS: aliased regions to stay under 64 KB static.
  __shared__ __align__(16) float sS[9216];     // 36 KB: part / pinfo / pout / concat
  __shared__ __align__(16) float qbuf[2048];   // 8 KB: q (ph1-2) then infob (ph4b-5)
  __shared__ __align__(16) float wbuf[1024];   // 4 KB: attn*mask weights [8][128]
  __shared__ __align__(16) float outb[2048];   // 8 KB: out rows [8][256]
  __shared__ float redmax[8][2];
  __shared__ float redsum[8][2];

  // ---- phase 1: load Q rows (512 float4) ----
  {
    const float4* qsrc = (const float4*)(Q + (b * 128 + n0) * 256);
    if (t < 512) ((float4*)qbuf)[t] = qsrc[t];
  }
  __syncthreads();

  // ---- phase 2: logits partials. thread = (m=t&127, qh=t>>7), 32 d each ----
  {
    int m = t & 127, qh = t >> 7;
    const float* kp = KT + (b * 256 + qh * 32) * 128 + m;
    float acc[8];
#pragma unroll
    for (int r = 0; r < 8; r++) acc[r] = 0.f;
    for (int i = 0; i < 32; i += 4) {
      float k0 = kp[(i + 0) * 128], k1 = kp[(i + 1) * 128];
      float k2 = kp[(i + 2) * 128], k3 = kp[(i + 3) * 128];
#pragma unroll
      for (int r = 0; r < 8; r++) {
        float4 q4 = *(const float4*)&qbuf[r * 256 + qh * 32 + i];
        acc[r] = fmaf(k0, q4.x, acc[r]);
        acc[r] = fmaf(k1, q4.y, acc[r]);
        acc[r] = fmaf(k2, q4.z, acc[r]);
        acc[r] = fmaf(k3, q4.w, acc[r]);
      }
    }
#pragma unroll
    for (int r = 0; r < 8; r++) sS[(qh * 128 + m) * 9 + r] = acc[r];
  }
  __syncthreads();

  // ---- phase 3: mask + scores + softmax. thread = (row rg=t>>7, m=t&127) ----
  {
    int rg = t >> 7, m = t & 127;
    float l = 0.f;
#pragma unroll
    for (int qq = 0; qq < 8; qq++) l += sS[(qq * 128 + m) * 9 + rg];
    l *= 0.0625f;                                   // 1/sqrt(256)
    int row = b * 128 + n0 + rg;
    float uu1 = u1[row * 128 + m];
    float uu2 = u2[row * 128 + m];
    float g1 = -__logf(-__logf(uu1 + 1e-20f) + 1e-20f);
    float g2 = -__logf(-__logf(uu2 + 1e-20f) + 1e-20f);
    float z = l + g1 - g2;                           // TAU = 1
    float mk = 1.0f / (1.0f + __expf(-z));
    o_mask[row * 128 + m] = mk;
    float score = l + __logf(mk + 1e-8f);
    float v = score;
#pragma unroll
    for (int off = 32; off >= 1; off >>= 1) v = fmaxf(v, __shfl_xor(v, off));
    if ((t & 63) == 0) redmax[rg][(t >> 6) & 1] = v;
    __syncthreads();
    float rmax = fmaxf(redmax[rg][0], redmax[rg][1]);
    float e = __expf(score - rmax);
    float s = e;
#pragma unroll
    for (int off = 32; off >= 1; off >>= 1) s += __shfl_xor(s, off);
    if ((t & 63) == 0) redsum[rg][(t >> 6) & 1] = s;
    __syncthreads();
    float rsum = redsum[rg][0] + redsum[rg][1];
    float attn = e / rsum;
    o_attn[row * 128 + m] = attn;
    wbuf[rg * 128 + m] = attn * mk;
  }
  __syncthreads();

  // ---- phase 4: info partials. thread = (h=t&255, mh=t>>8), 32 m each ----
  {
    int h = t & 255, mh = t >> 8;
    const float* vp = V + (b * 128 + mh * 32) * 256 + h;
    float acc[8];
#pragma unroll
    for (int r = 0; r < 8; r++) acc[r] = 0.f;
    for (int m2 = 0; m2 < 32; m2 += 4) {
      float v0 = vp[(m2 + 0) * 256], v1 = vp[(m2 + 1) * 256];
      float v2 = vp[(m2 + 2) * 256], v3 = vp[(m2 + 3) * 256];
#pragma unroll
      for (int r = 0; r < 8; r++) {
        float4 w4 = *(const float4*)&wbuf[r * 128 + mh * 32 + m2];
        acc[r] = fmaf(v0, w4.x, acc[r]);
        acc[r] = fmaf(v1, w4.y, acc[r]);
        acc[r] = fmaf(v2, w4.z, acc[r]);
        acc[r] = fmaf(v3, w4.w, acc[r]);
      }
    }
#pragma unroll
    for (int r = 0; r < 8; r++) sS[(mh * 8 + r) * 256 + h] = acc[r];
  }
  __syncthreads();

  // ---- phase 4b: infob = sum of 4 partials (into qbuf) ----
  {
    float2* inf2 = (float2*)qbuf;
    const float2* pin2 = (const float2*)sS;
    float2 x0 = pin2[t], x1 = pin2[t + 1024], x2 = pin2[t + 2048], x3 = pin2[t + 3072];
    inf2[t] = make_float2(x0.x + x1.x + x2.x + x3.x, x0.y + x1.y + x2.y + x3.y);
  }
  __syncthreads();

  // ---- phase 5: out partials. thread = (g=t&255, hh=t>>8), 64 h each ----
  {
    int g = t & 255, hh = t >> 8;
    const float* wop = WoT + (hh * 64) * 256 + g;
    float acc[8];
#pragma unroll
    for (int r = 0; r < 8; r++) acc[r] = 0.f;
    for (int hx = 0; hx < 64; hx += 4) {
      float w0 = wop[(hx + 0) * 256], w1 = wop[(hx + 1) * 256];
      float w2 = wop[(hx + 2) * 256], w3 = wop[(hx + 3) * 256];
#pragma unroll
      for (int r = 0; r < 8; r++) {
        float4 i4 = *(const float4*)&qbuf[r * 256 + hh * 64 + hx];
        acc[r] = fmaf(w0, i4.x, acc[r]);
        acc[r] = fmaf(w1, i4.y, acc[r]);
        acc[r] = fmaf(w2, i4.z, acc[r]);
        acc[r] = fmaf(w3, i4.w, acc[r]);
      }
    }
#pragma unroll
    for (int r = 0; r < 8; r++) sS[(hh * 8 + r) * 256 + g] = acc[r];
  }
  __syncthreads();

  // ---- phase 5b: combine + bias, write o_out + outb ----
  {
    const float2* po2 = (const float2*)sS;
    float2 y0 = po2[t], y1 = po2[t + 1024], y2 = po2[t + 2048], y3 = po2[t + 3072];
    float2 bo2 = ((const float2*)bo)[t & 127];
    float2 ov = make_float2(y0.x + y1.x + y2.x + y3.x + bo2.x,
                            y0.y + y1.y + y2.y + y3.y + bo2.y);
    ((float2*)(o_out + (b * 128 + n0) * 256))[t] = ov;
    ((float2*)outb)[t] = ov;
  }
  __syncthreads();

  // ---- phase 5c: build concat[8][384] in sS (pout dead) ----
  {
    // local + goals halves: 1024 entries
    int r = t >> 7, c = t & 127;
    int row = b * 128 + n0 + r;
    float v = (c < 64) ? agents_local[row * 64 + c] : goals[row * 64 + (c - 64)];
    sS[r * 384 + c] = v;
    // out part: 2048 entries, two passes
    int r2 = t >> 8, c2 = t & 255;
    sS[r2 * 384 + 128 + c2] = outb[r2 * 256 + c2];
    sS[(r2 + 4) * 384 + 128 + c2] = outb[(r2 + 4) * 256 + c2];
  }
  __syncthreads();

  // ---- phase 6: skill logits. thread = (out=t>>3: r,s ; part p=t&7 of 48) ----
  {
    int outi = t >> 3, p = t & 7;
    int r = outi >> 4, s = outi & 15;
    int row = b * 128 + n0 + r;
    const float* wsr = Wsm + s * 384 + p * 48;
    const float* cp = &sS[r * 384 + p * 48];
    float acc = 0.f;
#pragma unroll
    for (int i = 0; i < 48; i += 4) {
      float4 c4 = *(const float4*)&cp[i];
      acc = fmaf(wsr[i + 0], c4.x, acc);
      acc = fmaf(wsr[i + 1], c4.y, acc);
      acc = fmaf(wsr[i + 2], c4.z, acc);
      acc = fmaf(wsr[i + 3], c4.w, acc);
    }
    acc += __shfl_xor(acc, 1);
    acc += __shfl_xor(acc, 2);
    acc += __shfl_xor(acc, 4);
    if (p == 0) o_logit[row * 16 + s] = acc + bs[s];
  }
}

extern "C" void kernel_launch(void* const* d_in, const int* in_sizes, int n_in,
                              void* d_out, int out_size, void* d_ws, size_t ws_size,
                              hipStream_t stream) {
  const float* goals        = (const float*)d_in[0];
  const float* agents       = (const float*)d_in[1];
  const float* agents_local = (const float*)d_in[2];
  const float* u1           = (const float*)d_in[3];
  const float* u2           = (const float*)d_in[4];
  const float* Wq = (const float*)d_in[5];
  const float* bq = (const float*)d_in[6];
  const float* Wk = (const float*)d_in[7];
  const float* bk = (const float*)d_in[8];
  const float* Wv = (const float*)d_in[9];
  const float* bv = (const float*)d_in[10];
  const float* Wo = (const float*)d_in[11];
  const float* bo = (const float*)d_in[12];
  const float* Wsm = (const float*)d_in[13];
  const float* bs  = (const float*)d_in[14];
  float* out = (float*)d_out;
  float* ws  = (float*)d_ws;

  transpose_k<<<576, 256, 0, stream>>>(Wq, Wk, Wv, Wo, ws);
  proj_k<<<384, 256, 0, stream>>>(goals, agents, bq, bk, bv, ws);
  attn_k<<<256, 1024, 0, stream>>>(goals, agents_local, u1, u2, bo, Wsm, bs, ws, out);
}